// Round 5
// baseline (459.173 us; speedup 1.0000x reference)
//
#include <hip/hip_runtime.h>

// CRF loss: mean over batch of (logZ - path_score).  B=512, T=1024, K=48.
//
// R10c: DUAL-CHAIN consumer (3rd submit).  R10 died on a macro collision
// (buffer named BB); R10b died because #error on missing permlane builtins
// fires in hipcc's HOST pass where device builtins are invisible.  Fix:
// R9-style #if/#else with a __shfl_xor fallback (host pass compiles the
// fallback, device pass uses permlane — same as the working R9 binary).
//
// Theory (from R8/R9 post-mortems): step time ~450 cy with only ~36 cy MFMA
// issue + ~60 cy VALU; handshake/LDS-pinning surgery moved it -12% total =>
// consumer wave is STALL-SHADOW bound (MFMA dep latency / LDS round trip /
// poll residue).  Fix with big upside: interleave TWO independent
// recurrences (2 groups of 16 seqs) in ONE consumer wave — chain B issues
// inside chain A's stall shadow -> wall time ~halves if theory holds.
//   - 16 forward blocks x 32 seqs; ring 8 slots x 6640 B (stride-13 granule
//     layout kept from r7; chain-1 at +3328B, same bank pattern), PHASE=4.
//   - consumer: 18 MFMA/step (2 chains x 9, kt-major interleave: 6
//     independent MFMAs between dependent pairs); asm ds_read_b128 ledger:
//     poll -> issue S0,S1; step0 issue S2 wait 12; step1 issue S3 wait 12;
//     step2 wait 0 + cons-flag; step3 no wait. sched_barrier(0) after every
//     wait (rule #18).
//   - producers: exp OFF the gated path (in-place exp of prefetched buffer
//     during the previous phase); gated section = 8 ds_write_b128 + lgkm
//     drain + flag.  Loads 2 phases ahead.  Producer p owns slot p of each
//     phase + 1/3 of slot 3.
//   - rescale every 8 steps == step3 of odd phases (template RESC).
//   - capture ballot hoisted per-phase per-chain (template CAP0/CAP1).
// Kept: pre-exponentiated emissions (r6), stride-13 (r7), counted lgkm +
// sched_barrier (r9), permlane16/32_swap reduces (r9), setprio(1) consumer.
// Path-score blocks (16..527) share the launch and overlap the forward waves.

#define BB    512
#define TT    1024
#define KK    48
#define GG2   32                 // sequences per forward block (2 chains x 16)
#define NGRP2 16                 // forward blocks
#define NSLOT 8
#define SLOTB (415 * 16)         // 6640 B: granule (s*13+kg)*16, s<32, kg<12
#define PHASE 4
#define BLKT  256

typedef __attribute__((ext_vector_type(4))) short bf16x4;
typedef __attribute__((ext_vector_type(4))) float f32x4;
typedef __attribute__((ext_vector_type(4))) int   i32x4;

__device__ __forceinline__ f32x4 mfma16(bf16x4 a, bf16x4 b, f32x4 c) {
#if __has_builtin(__builtin_amdgcn_mfma_f32_16x16x16bf16_1k)
    return __builtin_amdgcn_mfma_f32_16x16x16bf16_1k(a, b, c, 0, 0, 0);
#else
    f32x4 d;
    asm volatile("v_mfma_f32_16x16x16_bf16 %0, %1, %2, %3"
                 : "=v"(d) : "v"(a), "v"(b), "v"(c));
    return d;
#endif
}

#if __has_builtin(__builtin_amdgcn_cvt_pk_bf16_f32)
typedef __attribute__((ext_vector_type(2))) __bf16 bf16x2_v;
__device__ __forceinline__ unsigned pk2(float lo, float hi) {
    union { bf16x2_v v; unsigned u; } x;
    x.v = __builtin_amdgcn_cvt_pk_bf16_f32(lo, hi);
    return x.u;
}
#else
__device__ __forceinline__ unsigned pk2(float lo, float hi) {
    return __builtin_amdgcn_perm(__float_as_uint(hi) + 0x8000u,
                                 __float_as_uint(lo) + 0x8000u,
                                 0x07060302u);
}
#endif
__device__ __forceinline__ bf16x4 pack4(float a, float b, float c, float d) {
    union { unsigned u[2]; bf16x4 v; } x;
    x.u[0] = pk2(a, b);
    x.u[1] = pk2(c, d);
    return x.v;
}

// VALU-speed lane^16 / lane^32 exchange.  Device pass: permlane builtins
// (present on gfx950, proven in R9).  Host pass / fallback: __shfl_xor
// (ds_bpermute) — never executed on device if permlane exists.  NO #error:
// the host pass can't see device builtins (R10b lesson).
#if __has_builtin(__builtin_amdgcn_permlane16_swap) && __has_builtin(__builtin_amdgcn_permlane32_swap)
__device__ __forceinline__ float swap16_max(float x) {
    auto p = __builtin_amdgcn_permlane16_swap(__float_as_int(x),
                                              __float_as_int(x), false, false);
    return fmaxf(__int_as_float(p[0]), __int_as_float(p[1]));
}
__device__ __forceinline__ float swap16_sum(float x) {
    auto p = __builtin_amdgcn_permlane16_swap(__float_as_int(x),
                                              __float_as_int(x), false, false);
    return __int_as_float(p[0]) + __int_as_float(p[1]);
}
__device__ __forceinline__ float swap32_max(float x) {
    auto p = __builtin_amdgcn_permlane32_swap(__float_as_int(x),
                                              __float_as_int(x), false, false);
    return fmaxf(__int_as_float(p[0]), __int_as_float(p[1]));
}
__device__ __forceinline__ float swap32_sum(float x) {
    auto p = __builtin_amdgcn_permlane32_swap(__float_as_int(x),
                                              __float_as_int(x), false, false);
    return __int_as_float(p[0]) + __int_as_float(p[1]);
}
#else
__device__ __forceinline__ float swap16_max(float x) { return fmaxf(x, __shfl_xor(x, 16, 64)); }
__device__ __forceinline__ float swap16_sum(float x) { return x + __shfl_xor(x, 16, 64); }
__device__ __forceinline__ float swap32_max(float x) { return fmaxf(x, __shfl_xor(x, 32, 64)); }
__device__ __forceinline__ float swap32_sum(float x) { return x + __shfl_xor(x, 32, 64); }
#endif

__device__ __forceinline__ float wave_reduce_sum(float v) {
    #pragma unroll
    for (int off = 32; off > 0; off >>= 1)
        v += __shfl_xor(v, off, 64);
    return v;
}

#define WAITLGKM(N) asm volatile("s_waitcnt lgkmcnt(" #N ")" ::: "memory")
#define SCHEDB()    __builtin_amdgcn_sched_barrier(0)

template<int OFF>
__device__ __forceinline__ void xread(unsigned base, f32x4& a, f32x4& b, f32x4& c3) {
    asm volatile("ds_read_b128 %0, %3 offset:%c4\n\t"
                 "ds_read_b128 %1, %3 offset:%c5\n\t"
                 "ds_read_b128 %2, %3 offset:%c6"
                 : "=&v"(a), "=&v"(b), "=&v"(c3)
                 : "v"(base), "i"(OFF), "i"(OFF + 64), "i"(OFF + 128));
}

// one recurrence step for BOTH chains; X in registers; no DS ops inside.
template<bool RESC, bool CAP0, bool CAP1>
__device__ __forceinline__ void dual_step(
    const bf16x4 (&A)[3][3], const f32x4 (&EF)[3],
    bf16x4 (&Bt)[2][3], float (&c)[2], float (&zc)[2], const int (&ln)[2],
    const f32x4 (&X0)[3], const f32x4 (&X1)[3], int t)
{
    const f32x4 z4 = {0.f, 0.f, 0.f, 0.f};
    // kt-major interleave: 6 independent MFMAs between dependent pairs.
    f32x4 d0 = mfma16(A[0][0], Bt[0][0], z4);
    f32x4 d1 = mfma16(A[1][0], Bt[0][0], z4);
    f32x4 d2 = mfma16(A[2][0], Bt[0][0], z4);
    f32x4 e0 = mfma16(A[0][0], Bt[1][0], z4);
    f32x4 e1 = mfma16(A[1][0], Bt[1][0], z4);
    f32x4 e2 = mfma16(A[2][0], Bt[1][0], z4);
    d0 = mfma16(A[0][1], Bt[0][1], d0);
    d1 = mfma16(A[1][1], Bt[0][1], d1);
    d2 = mfma16(A[2][1], Bt[0][1], d2);
    e0 = mfma16(A[0][1], Bt[1][1], e0);
    e1 = mfma16(A[1][1], Bt[1][1], e1);
    e2 = mfma16(A[2][1], Bt[1][1], e2);
    d0 = mfma16(A[0][2], Bt[0][2], d0);
    d1 = mfma16(A[1][2], Bt[0][2], d1);
    d2 = mfma16(A[2][2], Bt[0][2], d2);
    e0 = mfma16(A[0][2], Bt[1][2], e0);
    e1 = mfma16(A[1][2], Bt[1][2], e1);
    e2 = mfma16(A[2][2], Bt[1][2], e2);

    f32x4 Wa = d0 * X0[0], Wb = d1 * X0[1], Wc = d2 * X0[2];
    f32x4 Va = e0 * X1[0], Vb = e1 * X1[1], Vc = e2 * X1[2];

    if (RESC) {
        float m0 = fmaxf(
            fmaxf(fmaxf(fmaxf(Wa[0], Wa[1]), fmaxf(Wa[2], Wa[3])),
                  fmaxf(fmaxf(Wb[0], Wb[1]), fmaxf(Wb[2], Wb[3]))),
            fmaxf(fmaxf(Wc[0], Wc[1]), fmaxf(Wc[2], Wc[3])));
        float m1 = fmaxf(
            fmaxf(fmaxf(fmaxf(Va[0], Va[1]), fmaxf(Va[2], Va[3])),
                  fmaxf(fmaxf(Vb[0], Vb[1]), fmaxf(Vb[2], Vb[3]))),
            fmaxf(fmaxf(Vc[0], Vc[1]), fmaxf(Vc[2], Vc[3])));
        m0 = swap16_max(m0); m1 = swap16_max(m1);
        m0 = swap32_max(m0); m1 = swap32_max(m1);
        c[0] += __logf(m0);
        c[1] += __logf(m1);
        float r0 = __builtin_amdgcn_rcpf(m0);
        float r1 = __builtin_amdgcn_rcpf(m1);
        Wa *= r0; Wb *= r0; Wc *= r0;
        Va *= r1; Vb *= r1; Vc *= r1;
    }
    if (CAP0) {
        if (__ballot(t == ln[0])) {
            f32x4 Sv = Wa * EF[0] + Wb * EF[1] + Wc * EF[2];
            float S = (Sv[0] + Sv[1]) + (Sv[2] + Sv[3]);
            S = swap16_sum(S);
            S = swap32_sum(S);
            if (t == ln[0]) zc[0] = c[0] + __logf(S);
        }
    }
    if (CAP1) {
        if (__ballot(t == ln[1])) {
            f32x4 Sv = Va * EF[0] + Vb * EF[1] + Vc * EF[2];
            float S = (Sv[0] + Sv[1]) + (Sv[2] + Sv[3]);
            S = swap16_sum(S);
            S = swap32_sum(S);
            if (t == ln[1]) zc[1] = c[1] + __logf(S);
        }
    }
    Bt[0][0] = pack4(Wa[0], Wa[1], Wa[2], Wa[3]);
    Bt[0][1] = pack4(Wb[0], Wb[1], Wb[2], Wb[3]);
    Bt[0][2] = pack4(Wc[0], Wc[1], Wc[2], Wc[3]);
    Bt[1][0] = pack4(Va[0], Va[1], Va[2], Va[3]);
    Bt[1][1] = pack4(Vb[0], Vb[1], Vb[2], Vb[3]);
    Bt[1][2] = pack4(Vc[0], Vc[1], Vc[2], Vc[3]);
}

// one 4-step phase, both chains.  lgkm ledger (6 reads per step-slot):
// poll drains; issue S0,S1 (12); step0 issue S2, wait 12 (S0 done);
// step1 issue S3, wait 12 (S1 done); step2 wait 0 (all done) + cons flag;
// step3 no wait.  Flag at step2 gives producers ~2 extra steps of slack.
template<int SB, bool RESC, bool CAP0, bool CAP1>
__device__ __forceinline__ void cons_phase(
    int kc, unsigned xb0, unsigned xb1, unsigned flagAddr, unsigned consAddr,
    int lane, const bf16x4 (&A)[3][3], const f32x4 (&EF)[3],
    bf16x4 (&Bt)[2][3], float (&c)[2], float (&zc)[2], const int (&ln)[2])
{
    for (;;) {                        // one b128 read = all 3 producer flags
        i32x4 f;
        asm volatile("ds_read_b128 %0, %1\n\ts_waitcnt lgkmcnt(0)"
                     : "=&v"(f) : "v"(flagAddr) : "memory");
        SCHEDB();
        if (f[0] >= kc + 1 && f[1] >= kc + 1 && f[2] >= kc + 1) break;
    }
    const int t0 = 1 + kc * PHASE;
    constexpr int O0 = ((SB + 0) & 7) * SLOTB;
    constexpr int O1 = ((SB + 1) & 7) * SLOTB;
    constexpr int O2 = ((SB + 2) & 7) * SLOTB;
    constexpr int O3 = ((SB + 3) & 7) * SLOTB;
    f32x4 X[PHASE][2][3];
    xread<O0>(xb0, X[0][0][0], X[0][0][1], X[0][0][2]);
    xread<O0>(xb1, X[0][1][0], X[0][1][1], X[0][1][2]);
    xread<O1>(xb0, X[1][0][0], X[1][0][1], X[1][0][2]);
    xread<O1>(xb1, X[1][1][0], X[1][1][1], X[1][1][2]);
    // step 0
    xread<O2>(xb0, X[2][0][0], X[2][0][1], X[2][0][2]);
    xread<O2>(xb1, X[2][1][0], X[2][1][1], X[2][1][2]);
    WAITLGKM(12); SCHEDB();
    dual_step<false, CAP0, CAP1>(A, EF, Bt, c, zc, ln, X[0][0], X[0][1], t0 + 0);
    // step 1
    xread<O3>(xb0, X[3][0][0], X[3][0][1], X[3][0][2]);
    xread<O3>(xb1, X[3][1][0], X[3][1][1], X[3][1][2]);
    WAITLGKM(12); SCHEDB();
    dual_step<false, CAP0, CAP1>(A, EF, Bt, c, zc, ln, X[1][0], X[1][1], t0 + 1);
    // step 2: all reads complete; flag early (data is in registers)
    WAITLGKM(0); SCHEDB();
    if (lane == 0)
        asm volatile("ds_write_b32 %0, %1" :: "v"(consAddr), "v"(kc + 1) : "memory");
    dual_step<false, CAP0, CAP1>(A, EF, Bt, c, zc, ln, X[2][0], X[2][1], t0 + 2);
    // step 3 (rescale here on odd phases: t = 4k+4 divisible by 8)
    dual_step<RESC, CAP0, CAP1>(A, EF, Bt, c, zc, ln, X[3][0], X[3][1], t0 + 3);
}

__global__ __launch_bounds__(BLKT, 1) void crf_main_kernel(
    const float* __restrict__ emis,    // [B,T,K]
    const int*   __restrict__ lengths, // [B]
    const int*   __restrict__ tags,    // [B,T]
    const float* __restrict__ prior,   // [K]
    const float* __restrict__ trans,   // [K,K] trans[dest][src]
    const float* __restrict__ finalT,  // [K]
    float*       __restrict__ ws)      // [0..511] logZ, [512..1023] path
{
    __shared__ __align__(16) unsigned char ring[NSLOT * SLOTB];  // 51.9 KB
    __shared__ __align__(16) int prodCnt4[4];
    __shared__ int consCnt;

    const int tid  = threadIdx.x;
    const int wv   = tid >> 6;
    const int lane = tid & 63;

    // ================= path-score blocks =================
    if (blockIdx.x >= NGRP2) {
        const int b = blockIdx.x - NGRP2;
        int len = lengths[b];
        len = (len < 1) ? 1 : (len > TT ? TT : len);
        const float* eb = emis + (size_t)b * TT * KK;
        const int*   tg = tags + (size_t)b * TT;
        float ps = 0.0f;
        for (int t = tid; t < len; t += BLKT) {
            int cur = tg[t];
            float ev = eb[(size_t)t * KK + cur];
            float tr = (t == 0) ? prior[cur] : trans[cur * KK + tg[t - 1]];
            ps += ev + tr;
        }
        ps = wave_reduce_sum(ps);
        float* red = (float*)ring;
        if (lane == 0) red[wv] = ps;
        __syncthreads();
        if (tid == 0)
            ws[BB + b] = red[0] + red[1] + red[2] + red[3] + finalT[tg[len - 1]];
        return;
    }

    // ================= forward blocks =================
    const int g = blockIdx.x;

    if (tid == 0) {
        prodCnt4[0] = 0; prodCnt4[1] = 0; prodCnt4[2] = 0; prodCnt4[3] = 0;
        consCnt = 0;
    }
    __syncthreads();   // one-time flag init

    // gmax over the block's 32 sequences, computed identically by every wave
    int myLenL = lengths[g * GG2 + (lane & 31)];
    myLenL = (myLenL < 1) ? 1 : (myLenL > TT ? TT : myLenL);
    int gmax = myLenL;
    #pragma unroll
    for (int off = 32; off > 0; off >>= 1) {
        int o = __shfl_xor(gmax, off, 64);
        gmax = (o > gmax) ? o : gmax;
    }
    const int nsteps = gmax - 1;                 // steps t = 1..nsteps
    const int nphase = (nsteps + PHASE - 1) / PHASE;

    if (wv >= 1) {
        // ---------------- producer waves (1..3) ----------------
        // producer p fully writes slot p of each phase (384 granules = 6 per
        // lane) + 1/3 of slot 3 (2 per lane).  Global: coalesced 192B runs.
        // LDS: stride-13 (s*13+kg)*16 within slot.  exp runs OFF the gated
        // path (in-place on the buffer prefetched last phase).
        const int p = wv - 1;
        const float* gp[6]; int lo[6];
        #pragma unroll
        for (int q = 0; q < 6; ++q) {
            int gidx = lane + 64 * q;
            int s    = gidx / 12;
            int kg   = gidx - s * 12;
            gp[q]    = emis + (size_t)(g * GG2 + s) * (TT * KK) + kg * 4;
            lo[q]    = (s * 13 + kg) * 16;
        }
        const float* g3p[2]; int lo3[2];
        #pragma unroll
        for (int q = 0; q < 2; ++q) {
            int gidx = 128 * p + lane + 64 * q;
            int s    = gidx / 12;
            int kg   = gidx - s * 12;
            g3p[q]   = emis + (size_t)(g * GG2 + s) * (TT * KK) + kg * 4;
            lo3[q]   = (s * 13 + kg) * 16;
        }
        float4 PB0[8], PB1[8];   // staging buffers (NOT named BB: macro!)

#define PLOAD(buf, KP)                                                     \
        do {                                                               \
            int tp = 1 + 4 * (KP) + p;  tp = (tp > nsteps) ? nsteps : tp;  \
            int t3 = 1 + 4 * (KP) + 3;  t3 = (t3 > nsteps) ? nsteps : t3;  \
            _Pragma("unroll")                                              \
            for (int q = 0; q < 6; ++q)                                    \
                buf[q] = *reinterpret_cast<const float4*>(                 \
                    gp[q] + (size_t)tp * KK);                              \
            buf[6] = *reinterpret_cast<const float4*>(g3p[0] + (size_t)t3 * KK); \
            buf[7] = *reinterpret_cast<const float4*>(g3p[1] + (size_t)t3 * KK); \
        } while (0)

#define EXPIP(buf)                                                         \
        do {                                                               \
            _Pragma("unroll")                                              \
            for (int q = 0; q < 8; ++q) {                                  \
                float4 l = buf[q];                                         \
                l.x = __expf(l.x); l.y = __expf(l.y);                      \
                l.z = __expf(l.z); l.w = __expf(l.w);                      \
                buf[q] = l;                                                \
            }                                                              \
        } while (0)

#define PSTORE(buf, SP, S3)                                                \
        do {                                                               \
            unsigned char* bp = &ring[(SP) * SLOTB];                       \
            _Pragma("unroll")                                              \
            for (int q = 0; q < 6; ++q)                                    \
                *reinterpret_cast<float4*>(bp + lo[q]) = buf[q];           \
            unsigned char* b3 = &ring[(S3) * SLOTB];                       \
            *reinterpret_cast<float4*>(b3 + lo3[0]) = buf[6];              \
            *reinterpret_cast<float4*>(b3 + lo3[1]) = buf[7];              \
        } while (0)

        PLOAD(PB0, 0);
        PLOAD(PB1, 1);
        EXPIP(PB0);                    // phase 0 ready (waits its vmcnt)
        volatile int* vc = &consCnt;
        for (int k0 = 0; k0 < nphase; k0 += 2) {
            // ---- even phase k0: ring slots {1+p, 4} ----
            while (*vc < k0 - 1) __builtin_amdgcn_s_sleep(1);  // slot reuse gate
            asm volatile("" ::: "memory");
            PSTORE(PB0, 1 + p, 4);
            asm volatile("s_waitcnt lgkmcnt(0)" ::: "memory"); // data committed
            if (lane == 0) *(volatile int*)&prodCnt4[p] = k0 + 1;
            asm volatile("" ::: "memory");
            PLOAD(PB0, k0 + 2);        // 2 phases ahead, in flight
            EXPIP(PB1);                // phase k0+1 data -> ready
            // ---- odd phase k0+1: ring slots {5+p, 0} ----
            if (k0 + 1 < nphase) {
                while (*vc < k0) __builtin_amdgcn_s_sleep(1);
                asm volatile("" ::: "memory");
                PSTORE(PB1, 5 + p, 0);
                asm volatile("s_waitcnt lgkmcnt(0)" ::: "memory");
                if (lane == 0) *(volatile int*)&prodCnt4[p] = k0 + 2;
                asm volatile("" ::: "memory");
                PLOAD(PB1, k0 + 3);
                EXPIP(PB0);            // phase k0+2 data -> ready
            }
        }
#undef PLOAD
#undef EXPIP
#undef PSTORE
        return;
    }

    // ---------------- consumer (dual-chain MFMA) wave ----------------
    __builtin_amdgcn_s_setprio(1);
    const int col   = lane & 15;
    const int grp   = lane >> 4;
    const int rbase = grp * 4;
    const int seq0  = g * GG2 + col;
    const int seq1  = g * GG2 + 16 + col;

    int ln[2];
    {
        int l0 = lengths[seq0]; l0 = (l0 < 1) ? 1 : (l0 > TT ? TT : l0);
        int l1 = lengths[seq1]; l1 = (l1 < 1) ? 1 : (l1 > TT ? TT : l1);
        ln[0] = l0 - 1; ln[1] = l1 - 1;
    }

    // A tiles: bf16(exp(trans)); shared by both chains.
    bf16x4 A[3][3];
    #pragma unroll
    for (int mt = 0; mt < 3; ++mt) {
        #pragma unroll
        for (int kt = 0; kt < 3; ++kt) {
            float4 tv = *reinterpret_cast<const float4*>(
                trans + (size_t)(mt * 16 + col) * KK + kt * 16 + rbase);
            A[mt][kt] = pack4(__expf(tv.x), __expf(tv.y),
                              __expf(tv.z), __expf(tv.w));
        }
    }
    f32x4 EF[3];
    #pragma unroll
    for (int mt = 0; mt < 3; ++mt) {
        float4 fv = *reinterpret_cast<const float4*>(finalT + mt * 16 + rbase);
        EF[mt][0] = __expf(fv.x); EF[mt][1] = __expf(fv.y);
        EF[mt][2] = __expf(fv.z); EF[mt][3] = __expf(fv.w);
    }

    // init (t=0) both chains: w = exp(E0 + prior - c), c = per-column max
    bf16x4 Bt[2][3];
    float  c[2], zc[2];
    zc[0] = 0.0f; zc[1] = 0.0f;
    #pragma unroll
    for (int q = 0; q < 2; ++q) {
        const float* eb = emis + (size_t)(q ? seq1 : seq0) * TT * KK + rbase;
        f32x4 a0[3];
        #pragma unroll
        for (int mt = 0; mt < 3; ++mt) {
            f32x4 ev = *reinterpret_cast<const f32x4*>(eb + mt * 16);
            f32x4 pv = *reinterpret_cast<const f32x4*>(prior + mt * 16 + rbase);
            a0[mt] = ev + pv;
        }
        float mx = fmaxf(
            fmaxf(fmaxf(fmaxf(a0[0][0], a0[0][1]), fmaxf(a0[0][2], a0[0][3])),
                  fmaxf(fmaxf(a0[1][0], a0[1][1]), fmaxf(a0[1][2], a0[1][3]))),
            fmaxf(fmaxf(a0[2][0], a0[2][1]), fmaxf(a0[2][2], a0[2][3])));
        mx = swap16_max(mx);
        mx = swap32_max(mx);
        c[q] = mx;
        #pragma unroll
        for (int mt = 0; mt < 3; ++mt) {
            #pragma unroll
            for (int e = 0; e < 4; ++e) a0[mt][e] = __expf(a0[mt][e] - mx);
        }
        if (__ballot(ln[q] == 0)) {
            f32x4 Sv = a0[0] * EF[0] + a0[1] * EF[1] + a0[2] * EF[2];
            float S = (Sv[0] + Sv[1]) + (Sv[2] + Sv[3]);
            S = swap16_sum(S);
            S = swap32_sum(S);
            if (ln[q] == 0) zc[q] = mx + __logf(S);
        }
        Bt[q][0] = pack4(a0[0][0], a0[0][1], a0[0][2], a0[0][3]);
        Bt[q][1] = pack4(a0[1][0], a0[1][1], a0[1][2], a0[1][3]);
        Bt[q][2] = pack4(a0[2][0], a0[2][1], a0[2][2], a0[2][3]);
    }

    // lane's granule base in a slot: (col*13 + grp)*16 bytes; X1/X2 at
    // +64/+128.  Chain-1 sequences live at +3328 B (16*13*16), same banks.
    const unsigned xb0 = (unsigned)(size_t)&ring[0]
                       + (unsigned)((col * 13 + grp) * 16);
    const unsigned xb1 = xb0 + 3328u;
    const unsigned flagAddr = (unsigned)(size_t)&prodCnt4[0];
    const unsigned consAddr = (unsigned)(size_t)&consCnt;

#define DISPATCH(KC, SBv, RESCv)                                             \
    {                                                                        \
        const int tt0 = 1 + (KC) * PHASE;                                    \
        const bool ca = __ballot(ln[0] >= tt0 && ln[0] < tt0 + PHASE) != 0;  \
        const bool cb = __ballot(ln[1] >= tt0 && ln[1] < tt0 + PHASE) != 0;  \
        if (ca) {                                                            \
            if (cb) cons_phase<SBv, RESCv, true,  true >(KC, xb0, xb1,       \
                flagAddr, consAddr, lane, A, EF, Bt, c, zc, ln);             \
            else    cons_phase<SBv, RESCv, true,  false>(KC, xb0, xb1,       \
                flagAddr, consAddr, lane, A, EF, Bt, c, zc, ln);             \
        } else {                                                             \
            if (cb) cons_phase<SBv, RESCv, false, true >(KC, xb0, xb1,       \
                flagAddr, consAddr, lane, A, EF, Bt, c, zc, ln);             \
            else    cons_phase<SBv, RESCv, false, false>(KC, xb0, xb1,       \
                flagAddr, consAddr, lane, A, EF, Bt, c, zc, ln);             \
        }                                                                    \
    }

    for (int k0 = 0; k0 < nphase; k0 += 2) {
        DISPATCH(k0, 1, false);                          // t0 mod 8 == 1
        if (k0 + 1 < nphase) DISPATCH(k0 + 1, 5, true);  // t0 mod 8 == 5
    }
#undef DISPATCH

    if (lane < 16) {
        ws[seq0] = zc[0];
        ws[seq1] = zc[1];
    }
}

__global__ __launch_bounds__(512) void reduce_mean_kernel(
    const float* __restrict__ ws, float* __restrict__ out)
{
    __shared__ float sm[8];
    int tid = threadIdx.x;          // 512 threads = 8 waves
    float x = ws[tid] - ws[BB + tid];   // logZ_b - path_b
    x = wave_reduce_sum(x);
    if ((tid & 63) == 0) sm[tid >> 6] = x;
    __syncthreads();
    if (tid < 8) {
        float y = sm[tid];
        y += __shfl_xor(y, 1, 64);
        y += __shfl_xor(y, 2, 64);
        y += __shfl_xor(y, 4, 64);
        if (tid == 0) out[0] = y * (1.0f / 512.0f);
    }
}

extern "C" void kernel_launch(void* const* d_in, const int* in_sizes, int n_in,
                              void* d_out, int out_size, void* d_ws, size_t ws_size,
                              hipStream_t stream) {
    const float* emis    = (const float*)d_in[0];
    const int*   lengths = (const int*)  d_in[1];
    const int*   tags    = (const int*)  d_in[2];
    const float* prior   = (const float*)d_in[3];
    const float* trans   = (const float*)d_in[4];
    const float* finalT  = (const float*)d_in[5];

    float* ws  = (float*)d_ws;     // [0..511] logZ, [512..1023] path score
    float* out = (float*)d_out;

    crf_main_kernel<<<NGRP2 + BB, BLKT, 0, stream>>>(emis, lengths, tags, prior,
                                                     trans, finalT, ws);
    reduce_mean_kernel<<<1, 512, 0, stream>>>(ws, out);
}

// Round 9
// 333.026 us; speedup vs baseline: 1.3788x; 1.3788x over previous
//
#include <hip/hip_runtime.h>

// CRF loss: mean over batch of (logZ - path_score).  B=512, T=1024, K=48.
//
// R14: SELF-FEEDING WAVES in PURE C++ — no inline asm anywhere.
//
// History: R11/R12/R13 (asm global_load streaming) -> NaN / abort / abort.
// All addresses verified in-bounds; the vmcnt ledger verified; the R13
// "drain before exit" fix changed nothing => the fault lives somewhere in
// the inline-asm global_load path and resists inspection.  This round
// removes the entire asm class and tests the STRUCTURAL theory cleanly.
//
// Theory (R9 vs R10c evidence, still untested): a lone wave executes at a
// flat ~7 cy/instruction regardless of mix -> issue-cadence bound, so the
// 3-producer/1-consumer LDS pipeline (R7-R9, best 191 us) concentrated all
// serial work in one wave and wasted 3 waves + LDS round trips + handshakes
// feeding it.  Here every forward wave is a complete recurrence engine:
//   - 32 forward blocks x 1 wave x 16 seqs = 512 (waves 1-3 exit at once).
//   - No LDS, no flags, no __syncthreads, no asm in the forward path.
//   - Emissions stream HBM->VGPR with plain f32x4 loads, double-buffered
//     by 4-step phase: loads for phase k+1 issue (program order) before any
//     consumption of phase k -> >=4 steps issue-to-use distance even with
//     zero scheduler help; hipcc emits its own counted vmcnt waits for
//     loads it can see (guide G7).  X buffers = 96 VGPR, total ~170.
//   - exp at consume time (12 quarter-rate v_exp/step on this wave).
//   - Per-step clamped t (min(t,nsteps)) = the R9-proven uniform-tail
//     pattern; steps past a column's len-1 compute harmless garbage
//     (zc already captured at t == len-1).
// Kept (all proven in the passing R9 run): 9-MFMA chained step (D-layout ==
// B-layout feeds next B), rescale every 8 steps (last step of odd phases),
// per-phase hoisted capture ballot, permlane16/32 swaps with __shfl
// fallback (host pass cannot see device builtins - R10b lesson), cvt_pk
// bf16 pack, col-wise (xor 1,2,4,8) + readfirstlane uniform nsteps (R12
// fix), setprio(1).  Path-score blocks (32..543) share the launch.

#define BB    512
#define TT    1024
#define KK    48
#define NGRP  32
#define PH    4
#define BLKT  256

typedef __attribute__((ext_vector_type(4))) short bf16x4;
typedef __attribute__((ext_vector_type(4))) float f32x4;

__device__ __forceinline__ f32x4 mfma16(bf16x4 a, bf16x4 b, f32x4 c) {
#if __has_builtin(__builtin_amdgcn_mfma_f32_16x16x16bf16_1k)
    return __builtin_amdgcn_mfma_f32_16x16x16bf16_1k(a, b, c, 0, 0, 0);
#else
    f32x4 d;
    asm volatile("v_mfma_f32_16x16x16_bf16 %0, %1, %2, %3"
                 : "=v"(d) : "v"(a), "v"(b), "v"(c));
    return d;
#endif
}

#if __has_builtin(__builtin_amdgcn_cvt_pk_bf16_f32)
typedef __attribute__((ext_vector_type(2))) __bf16 bf16x2_v;
__device__ __forceinline__ unsigned pk2(float lo, float hi) {
    union { bf16x2_v v; unsigned u; } x;
    x.v = __builtin_amdgcn_cvt_pk_bf16_f32(lo, hi);
    return x.u;
}
#else
__device__ __forceinline__ unsigned pk2(float lo, float hi) {
    return __builtin_amdgcn_perm(__float_as_uint(hi) + 0x8000u,
                                 __float_as_uint(lo) + 0x8000u,
                                 0x07060302u);
}
#endif
__device__ __forceinline__ bf16x4 pack4(float a, float b, float c, float d) {
    union { unsigned u[2]; bf16x4 v; } x;
    x.u[0] = pk2(a, b);
    x.u[1] = pk2(c, d);
    return x.v;
}

// VALU-speed lane^16 / lane^32 exchange; __shfl fallback for the host pass
// (device builtins invisible there - R10b lesson; NO #error).
#if __has_builtin(__builtin_amdgcn_permlane16_swap) && __has_builtin(__builtin_amdgcn_permlane32_swap)
__device__ __forceinline__ float swap16_max(float x) {
    auto p = __builtin_amdgcn_permlane16_swap(__float_as_int(x),
                                              __float_as_int(x), false, false);
    return fmaxf(__int_as_float(p[0]), __int_as_float(p[1]));
}
__device__ __forceinline__ float swap16_sum(float x) {
    auto p = __builtin_amdgcn_permlane16_swap(__float_as_int(x),
                                              __float_as_int(x), false, false);
    return __int_as_float(p[0]) + __int_as_float(p[1]);
}
__device__ __forceinline__ float swap32_max(float x) {
    auto p = __builtin_amdgcn_permlane32_swap(__float_as_int(x),
                                              __float_as_int(x), false, false);
    return fmaxf(__int_as_float(p[0]), __int_as_float(p[1]));
}
__device__ __forceinline__ float swap32_sum(float x) {
    auto p = __builtin_amdgcn_permlane32_swap(__float_as_int(x),
                                              __float_as_int(x), false, false);
    return __int_as_float(p[0]) + __int_as_float(p[1]);
}
#else
__device__ __forceinline__ float swap16_max(float x) { return fmaxf(x, __shfl_xor(x, 16, 64)); }
__device__ __forceinline__ float swap16_sum(float x) { return x + __shfl_xor(x, 16, 64); }
__device__ __forceinline__ float swap32_max(float x) { return fmaxf(x, __shfl_xor(x, 32, 64)); }
__device__ __forceinline__ float swap32_sum(float x) { return x + __shfl_xor(x, 32, 64); }
#endif

__device__ __forceinline__ float wave_reduce_sum(float v) {
    #pragma unroll
    for (int off = 32; off > 0; off >>= 1)
        v += __shfl_xor(v, off, 64);
    return v;
}

__device__ __forceinline__ f32x4 exp4(f32x4 x) {
    f32x4 r;
    r[0] = __expf(x[0]); r[1] = __expf(x[1]);
    r[2] = __expf(x[2]); r[3] = __expf(x[3]);
    return r;
}

// one 4-step phase consumed from register buffer X (loaded last phase).
// RESC: rescale at the last step (odd phases -> t = 8k+8 cadence).
template<bool RESC, bool CAP>
__device__ __forceinline__ void run_phase(
    int t0, const f32x4 (&X)[PH][3],
    const bf16x4 (&A)[3][3], const f32x4 (&EF)[3],
    bf16x4& Bt0, bf16x4& Bt1, bf16x4& Bt2,
    float& c, float& zc, int ln)
{
    const f32x4 z4 = {0.f, 0.f, 0.f, 0.f};
    #pragma unroll
    for (int S = 0; S < PH; ++S) {
        f32x4 E0 = exp4(X[S][0]);
        f32x4 E1 = exp4(X[S][1]);
        f32x4 E2 = exp4(X[S][2]);
        f32x4 d0 = mfma16(A[0][0], Bt0, z4);
        f32x4 d1 = mfma16(A[1][0], Bt0, z4);
        f32x4 d2 = mfma16(A[2][0], Bt0, z4);
        d0 = mfma16(A[0][1], Bt1, d0);
        d1 = mfma16(A[1][1], Bt1, d1);
        d2 = mfma16(A[2][1], Bt1, d2);
        d0 = mfma16(A[0][2], Bt2, d0);
        d1 = mfma16(A[1][2], Bt2, d1);
        d2 = mfma16(A[2][2], Bt2, d2);
        f32x4 Wa = d0 * E0, Wb = d1 * E1, Wc = d2 * E2;
        if (RESC && S == PH - 1) {       // t = 8k+8: rescale
            float mx = fmaxf(
                fmaxf(fmaxf(fmaxf(Wa[0], Wa[1]), fmaxf(Wa[2], Wa[3])),
                      fmaxf(fmaxf(Wb[0], Wb[1]), fmaxf(Wb[2], Wb[3]))),
                fmaxf(fmaxf(Wc[0], Wc[1]), fmaxf(Wc[2], Wc[3])));
            mx = swap16_max(mx);
            mx = swap32_max(mx);
            c += __logf(mx);
            float rm = __builtin_amdgcn_rcpf(mx);
            Wa *= rm; Wb *= rm; Wc *= rm;
        }
        if (CAP) {
            if (__ballot(t0 + S == ln)) {
                f32x4 Sv = Wa * EF[0] + Wb * EF[1] + Wc * EF[2];
                float Ssum = (Sv[0] + Sv[1]) + (Sv[2] + Sv[3]);
                Ssum = swap16_sum(Ssum);
                Ssum = swap32_sum(Ssum);
                if (t0 + S == ln) zc = c + __logf(Ssum);
            }
        }
        Bt0 = pack4(Wa[0], Wa[1], Wa[2], Wa[3]);
        Bt1 = pack4(Wb[0], Wb[1], Wb[2], Wb[3]);
        Bt2 = pack4(Wc[0], Wc[1], Wc[2], Wc[3]);
    }
}

__global__ __launch_bounds__(BLKT, 1) void crf_main_kernel(
    const float* __restrict__ emis,    // [B,T,K]
    const int*   __restrict__ lengths, // [B]
    const int*   __restrict__ tags,    // [B,T]
    const float* __restrict__ prior,   // [K]
    const float* __restrict__ trans,   // [K,K] trans[dest][src]
    const float* __restrict__ finalT,  // [K]
    float*       __restrict__ ws)      // [0..511] logZ, [512..1023] path
{
    __shared__ float red[4];           // path blocks only

    const int tid  = threadIdx.x;
    const int wv   = tid >> 6;
    const int lane = tid & 63;

    // ================= path-score blocks =================
    if (blockIdx.x >= NGRP) {
        const int b = blockIdx.x - NGRP;
        int len = lengths[b];
        len = (len < 1) ? 1 : (len > TT ? TT : len);
        const float* eb = emis + (size_t)b * TT * KK;
        const int*   tg = tags + (size_t)b * TT;
        float ps = 0.0f;
        for (int t = tid; t < len; t += BLKT) {
            int cur = tg[t];
            float ev = eb[(size_t)t * KK + cur];
            float tr = (t == 0) ? prior[cur] : trans[cur * KK + tg[t - 1]];
            ps += ev + tr;
        }
        ps = wave_reduce_sum(ps);
        if (lane == 0) red[wv] = ps;
        __syncthreads();
        if (tid == 0)
            ws[BB + b] = red[0] + red[1] + red[2] + red[3] + finalT[tg[len - 1]];
        return;
    }

    // ============ forward blocks: 1 self-feeding wave per block ============
    if (wv != 0) return;               // waves 1..3 exit immediately
    __builtin_amdgcn_s_setprio(1);     // vs transient co-resident path blocks

    const int g     = blockIdx.x;
    const int col   = lane & 15;
    const int grp   = lane >> 4;
    const int rbase = grp * 4;
    const int seq   = g * 16 + col;    // this wave's 16 seqs

    int myLen = lengths[seq];
    myLen = (myLen < 1) ? 1 : (myLen > TT ? TT : myLen);
    const int ln = myLen - 1;
    // wave max over the 16 COLS (xor 1,2,4,8 within each 16-lane group ->
    // identical in all groups), then to SGPR: uniform, zero divergence.
    int gm = myLen;
    #pragma unroll
    for (int off = 1; off < 16; off <<= 1) {
        int o = __shfl_xor(gm, off, 64);
        gm = (o > gm) ? o : gm;
    }
    const int nsteps = __builtin_amdgcn_readfirstlane(gm) - 1;  // t = 1..nsteps
    const int nphase = (nsteps + PH - 1) / PH;

    // A tiles: bf16(exp(trans)); A[m][k]: m = mt*16+col, k = kt*16+rbase+j
    bf16x4 A[3][3];
    #pragma unroll
    for (int mt = 0; mt < 3; ++mt) {
        #pragma unroll
        for (int kt = 0; kt < 3; ++kt) {
            float4 tv = *reinterpret_cast<const float4*>(
                trans + (size_t)(mt * 16 + col) * KK + kt * 16 + rbase);
            A[mt][kt] = pack4(__expf(tv.x), __expf(tv.y),
                              __expf(tv.z), __expf(tv.w));
        }
    }
    f32x4 EF[3];
    #pragma unroll
    for (int mt = 0; mt < 3; ++mt) {
        float4 fv = *reinterpret_cast<const float4*>(finalT + mt * 16 + rbase);
        EF[mt][0] = __expf(fv.x); EF[mt][1] = __expf(fv.y);
        EF[mt][2] = __expf(fv.z); EF[mt][3] = __expf(fv.w);
    }

    const float* eb_lane = emis + (size_t)seq * TT * KK + rbase;

    // init (t=0): w = exp(E0 + prior - c), c = per-column max
    bf16x4 Bt0, Bt1, Bt2;
    float  c, zc = 0.0f;
    {
        f32x4 a0[3];
        #pragma unroll
        for (int mt = 0; mt < 3; ++mt) {
            f32x4 ev = *reinterpret_cast<const f32x4*>(eb_lane + mt * 16);
            f32x4 pv = *reinterpret_cast<const f32x4*>(prior + mt * 16 + rbase);
            a0[mt] = ev + pv;
        }
        float mx = fmaxf(
            fmaxf(fmaxf(fmaxf(a0[0][0], a0[0][1]), fmaxf(a0[0][2], a0[0][3])),
                  fmaxf(fmaxf(a0[1][0], a0[1][1]), fmaxf(a0[1][2], a0[1][3]))),
            fmaxf(fmaxf(a0[2][0], a0[2][1]), fmaxf(a0[2][2], a0[2][3])));
        mx = swap16_max(mx);
        mx = swap32_max(mx);
        c = mx;
        #pragma unroll
        for (int mt = 0; mt < 3; ++mt) {
            #pragma unroll
            for (int e = 0; e < 4; ++e) a0[mt][e] = __expf(a0[mt][e] - mx);
        }
        if (__ballot(ln == 0)) {
            f32x4 Sv = a0[0] * EF[0] + a0[1] * EF[1] + a0[2] * EF[2];
            float Ssum = (Sv[0] + Sv[1]) + (Sv[2] + Sv[3]);
            Ssum = swap16_sum(Ssum);
            Ssum = swap32_sum(Ssum);
            if (ln == 0) zc = mx + __logf(Ssum);
        }
        Bt0 = pack4(a0[0][0], a0[0][1], a0[0][2], a0[0][3]);
        Bt1 = pack4(a0[1][0], a0[1][1], a0[1][2], a0[1][3]);
        Bt2 = pack4(a0[2][0], a0[2][1], a0[2][2], a0[2][3]);
    }

    // double-buffered phase prefetch: XA/XB, 48+48 = 96 VGPR.
    // per-step clamped t (min(t, nsteps)): always in-bounds; steps past a
    // column's ln compute discarded values (zc already captured).
    f32x4 XA[PH][3], XB[PH][3];

#define LDPH(Xb, KP)                                                       \
    do {                                                                   \
        _Pragma("unroll")                                                  \
        for (int S = 0; S < PH; ++S) {                                     \
            int tc = 1 + PH * (KP) + S;                                    \
            tc = (tc > nsteps) ? nsteps : tc;                              \
            const float* pp = eb_lane + (size_t)tc * KK;                   \
            Xb[S][0] = *reinterpret_cast<const f32x4*>(pp);                \
            Xb[S][1] = *reinterpret_cast<const f32x4*>(pp + 16);           \
            Xb[S][2] = *reinterpret_cast<const f32x4*>(pp + 32);           \
        }                                                                  \
    } while (0)

    LDPH(XA, 0);
    for (int k = 0; k < nphase; k += 2) {
        LDPH(XB, k + 1);               // prefetch phase k+1 (clamped, safe)
        {
            const int t0 = 1 + k * PH;
            const bool cap = __ballot(ln >= t0 && ln < t0 + PH) != 0;
            if (cap) run_phase<false, true >(t0, XA, A, EF, Bt0, Bt1, Bt2, c, zc, ln);
            else     run_phase<false, false>(t0, XA, A, EF, Bt0, Bt1, Bt2, c, zc, ln);
        }
        if (k + 1 < nphase) {
            LDPH(XA, k + 2);           // prefetch phase k+2
            const int t0 = 1 + (k + 1) * PH;
            const bool cap = __ballot(ln >= t0 && ln < t0 + PH) != 0;
            if (cap) run_phase<true, true >(t0, XB, A, EF, Bt0, Bt1, Bt2, c, zc, ln);
            else     run_phase<true, false>(t0, XB, A, EF, Bt0, Bt1, Bt2, c, zc, ln);
        }
    }
#undef LDPH

    if (lane < 16) ws[seq] = zc;       // 4 grp replicas agree
}

__global__ __launch_bounds__(512) void reduce_mean_kernel(
    const float* __restrict__ ws, float* __restrict__ out)
{
    __shared__ float sm[8];
    int tid = threadIdx.x;          // 512 threads = 8 waves
    float x = ws[tid] - ws[BB + tid];   // logZ_b - path_b
    x = wave_reduce_sum(x);
    if ((tid & 63) == 0) sm[tid >> 6] = x;
    __syncthreads();
    if (tid < 8) {
        float y = sm[tid];
        y += __shfl_xor(y, 1, 64);
        y += __shfl_xor(y, 2, 64);
        y += __shfl_xor(y, 4, 64);
        if (tid == 0) out[0] = y * (1.0f / 512.0f);
    }
}

extern "C" void kernel_launch(void* const* d_in, const int* in_sizes, int n_in,
                              void* d_out, int out_size, void* d_ws, size_t ws_size,
                              hipStream_t stream) {
    const float* emis    = (const float*)d_in[0];
    const int*   lengths = (const int*)  d_in[1];
    const int*   tags    = (const int*)  d_in[2];
    const float* prior   = (const float*)d_in[3];
    const float* trans   = (const float*)d_in[4];
    const float* finalT  = (const float*)d_in[5];

    float* ws  = (float*)d_ws;     // [0..511] logZ, [512..1023] path score
    float* out = (float*)d_out;

    crf_main_kernel<<<NGRP + BB, BLKT, 0, stream>>>(emis, lengths, tags, prior,
                                                    trans, finalT, ws);
    reduce_mean_kernel<<<1, 512, 0, stream>>>(ws, out);
}